// Round 1
// baseline (586.973 us; speedup 1.0000x reference)
//
#include <hip/hip_runtime.h>
#include <math.h>

// ---------------- sizes ----------------
#define Bn 8
#define Wn 20
#define Mn 512
#define Fn 16
#define Hn 128
#define HALFn 64
#define Kn 10
#define NSEQ (Bn*Mn)          // 4096

__device__ __forceinline__ float sigmoidf_(float x) {
  return 1.0f / (1.0f + __expf(-x));
}
__device__ __forceinline__ float tanhf_(float x) {
  float xx = fminf(fmaxf(x, -15.f), 15.f);
  float e = __expf(2.f * xx);
  return (e - 1.f) / (e + 1.f);
}
__device__ __forceinline__ float reluf_(float x) { return fmaxf(x, 0.f); }

// ---------------- prep: transpose Whh (384,128) -> WhhT (128,384) ----------------
__global__ __launch_bounds__(256) void whht_kernel(const float* __restrict__ Whh,
                                                   float* __restrict__ WhhT) {
  int idx = blockIdx.x * 256 + threadIdx.x;
  if (idx < 384 * 128) {
    int g = idx >> 7, k = idx & 127;
    WhhT[k * 384 + g] = Whh[idx];
  }
}

// ---------------- GRU: 8 seqs per block, 384 threads (gate-parallel) ----------------
__global__ __launch_bounds__(384) void gru_kernel(
    const float* __restrict__ X, const float* __restrict__ WhhT,
    const float* __restrict__ Wih, const float* __restrict__ bih,
    const float* __restrict__ bhh, float* __restrict__ last_hid) {
  const int g = threadIdx.x;          // 0..383
  const int gate = g >> 7;            // 0=r,1=z,2=n
  const int j = g & 127;
  const int n0 = blockIdx.x * 8;
  const int b = n0 >> 9;
  const int m0 = n0 & 511;

  __shared__ float h_s[8][128];
  __shared__ float xt_s[8][16];
  __shared__ float r_s[8][128];
  __shared__ float zn_s[2][8][128];

  float wih[16];
#pragma unroll
  for (int f = 0; f < 16; ++f) wih[f] = Wih[g * 16 + f];
  const float xb = bih[g];
  const float hb = bhh[g];

  if (g < 128) {
#pragma unroll
    for (int s = 0; s < 8; ++s) h_s[s][j] = 0.f;
  }
  __syncthreads();

  const float* Xbase = X + ((long)b * Wn * Mn + m0) * Fn;
  for (int t = 0; t < Wn; ++t) {
    float xv = 0.f;
    if (g < 128) xv = Xbase[(long)t * Mn * Fn + g];

    float acc[8] = {0, 0, 0, 0, 0, 0, 0, 0};
#pragma unroll 4
    for (int k4 = 0; k4 < 128; k4 += 4) {
      float w0 = WhhT[(k4 + 0) * 384 + g];
      float w1 = WhhT[(k4 + 1) * 384 + g];
      float w2 = WhhT[(k4 + 2) * 384 + g];
      float w3 = WhhT[(k4 + 3) * 384 + g];
#pragma unroll
      for (int s = 0; s < 8; ++s) {
        float4 h4 = *(const float4*)&h_s[s][k4];
        acc[s] = fmaf(h4.x, w0, acc[s]);
        acc[s] = fmaf(h4.y, w1, acc[s]);
        acc[s] = fmaf(h4.z, w2, acc[s]);
        acc[s] = fmaf(h4.w, w3, acc[s]);
      }
    }
    if (g < 128) xt_s[g >> 4][g & 15] = xv;
    __syncthreads();  // xt ready; everyone done reading h_s

    float gx[8];
#pragma unroll
    for (int s = 0; s < 8; ++s) {
      float a = xb;
#pragma unroll
      for (int f4 = 0; f4 < 16; f4 += 4) {
        float4 x4 = *(const float4*)&xt_s[s][f4];
        a = fmaf(x4.x, wih[f4 + 0], a);
        a = fmaf(x4.y, wih[f4 + 1], a);
        a = fmaf(x4.z, wih[f4 + 2], a);
        a = fmaf(x4.w, wih[f4 + 3], a);
      }
      gx[s] = a;
    }

    if (gate == 0) {
#pragma unroll
      for (int s = 0; s < 8; ++s) r_s[s][j] = sigmoidf_(gx[s] + acc[s] + hb);
    } else if (gate == 1) {
#pragma unroll
      for (int s = 0; s < 8; ++s) zn_s[0][s][j] = sigmoidf_(gx[s] + acc[s] + hb);
    }
    __syncthreads();  // r ready
    if (gate == 2) {
#pragma unroll
      for (int s = 0; s < 8; ++s)
        zn_s[1][s][j] = tanhf_(gx[s] + r_s[s][j] * (acc[s] + hb));
    }
    __syncthreads();  // z,n ready
    if (g < 128) {
#pragma unroll
      for (int s = 0; s < 8; ++s) {
        float z = zn_s[0][s][j], n = zn_s[1][s][j];
        h_s[s][j] = (1.f - z) * n + z * h_s[s][j];
      }
    }
    __syncthreads();  // h updated
  }
  if (g < 128) {
#pragma unroll
    for (int s = 0; s < 8; ++s) last_hid[(long)(n0 + s) * Hn + j] = h_s[s][j];
  }
}

// ---------------- p1/p2: per-row projections (4 rows/block) ----------------
__global__ __launch_bounds__(128) void attn_p_kernel(
    const float* __restrict__ last_hid, const float* __restrict__ W1,
    const float* __restrict__ W2, const float* __restrict__ b1,
    float* __restrict__ p1, float* __restrict__ p2) {
  int r0 = blockIdx.x * 4;
  int t = threadIdx.x;
  __shared__ float hs[4][128];
  for (int idx = t; idx < 512; idx += 128)
    hs[idx >> 7][idx & 127] = last_hid[(long)r0 * 128 + idx];
  __syncthreads();
  int k = t & 63;
  const float* Wp = (t < 64) ? W1 : W2;
  float a0, a1, a2, a3;
  a0 = a1 = a2 = a3 = (t < 64) ? b1[k] : 0.f;
  for (int h = 0; h < 128; h += 4) {
    float4 w = *(const float4*)&Wp[k * 128 + h];
    float4 q0 = *(const float4*)&hs[0][h];
    float4 q1 = *(const float4*)&hs[1][h];
    float4 q2 = *(const float4*)&hs[2][h];
    float4 q3 = *(const float4*)&hs[3][h];
    a0 += q0.x * w.x + q0.y * w.y + q0.z * w.z + q0.w * w.w;
    a1 += q1.x * w.x + q1.y * w.y + q1.z * w.z + q1.w * w.w;
    a2 += q2.x * w.x + q2.y * w.y + q2.z * w.z + q2.w * w.w;
    a3 += q3.x * w.x + q3.y * w.y + q3.z * w.z + q3.w * w.w;
  }
  float* outp = (t < 64) ? p1 : p2;
  outp[(r0 + 0) * 64 + k] = a0;
  outp[(r0 + 1) * 64 + k] = a1;
  outp[(r0 + 2) * 64 + k] = a2;
  outp[(r0 + 3) * 64 + k] = a3;
}

// ---------------- a_mx (raw): 16x16 tile per block ----------------
__global__ __launch_bounds__(256) void amx_kernel(
    const float* __restrict__ p1, const float* __restrict__ p2,
    const float* __restrict__ V, const float* __restrict__ bv,
    float* __restrict__ amx) {
  int tid = threadIdx.x;
  int j0 = blockIdx.x * 16, i0 = blockIdx.y * 16, bz = blockIdx.z;
  __shared__ float p1s[16][68];
  __shared__ float p2s[16][68];
  __shared__ float Vs[64];
  if (tid < 64) Vs[tid] = V[tid];
#pragma unroll
  for (int l = 0; l < 4; ++l) {
    int idx = l * 256 + tid;
    int rr = idx >> 6, k = idx & 63;
    p1s[rr][k] = p1[(long)(bz * 512 + j0 + rr) * 64 + k];
    p2s[rr][k] = p2[(long)(bz * 512 + i0 + rr) * 64 + k];
  }
  __syncthreads();
  int ii = tid >> 4, jj = tid & 15;
  float acc = 0.f;
#pragma unroll 4
  for (int k = 0; k < 64; ++k) {
    float pre = p1s[jj][k] + p2s[ii][k];
    float e = (pre > 0.f) ? pre : (__expf(pre) - 1.f);
    acc = fmaf(e, Vs[k], acc);
  }
  amx[((long)bz * 512 + i0 + ii) * 512 + j0 + jj] = acc + bv[0];
}

// ---------------- column L2 norm over i (dim=1) ----------------
__global__ __launch_bounds__(256) void colnorm_kernel(const float* __restrict__ amx,
                                                      float* __restrict__ scale) {
  int b = blockIdx.y;
  int j0 = blockIdx.x * 32;
  int jl = threadIdx.x & 31, ip = threadIdx.x >> 5;
  const float* base = amx + (long)b * 512 * 512;
  float ss = 0.f;
  for (int i = ip; i < 512; i += 8) {
    float v = base[(long)i * 512 + j0 + jl];
    ss = fmaf(v, v, ss);
  }
  __shared__ float red[8][33];
  red[ip][jl] = ss;
  __syncthreads();
  if (threadIdx.x < 32) {
    float s = 0.f;
#pragma unroll
    for (int p = 0; p < 8; ++p) s += red[p][threadIdx.x];
    scale[b * 512 + j0 + threadIdx.x] = 1.f / fmaxf(sqrtf(s), 1e-12f);
  }
}

// ---------------- apply column scale in place ----------------
__global__ __launch_bounds__(256) void scale_kernel(float* __restrict__ amx,
                                                    const float* __restrict__ scale) {
  long e = ((long)blockIdx.x * 256 + threadIdx.x) * 4;
  int j = (int)(e & 511);
  int b = (int)(e >> 18);
  float4 v = *(float4*)&amx[e];
  const float* sc = &scale[b * 512 + j];
  v.x *= sc[0]; v.y *= sc[1]; v.z *= sc[2]; v.w *= sc[3];
  *(float4*)&amx[e] = v;
}

// ---------------- per-node convs -> r_l (b,m,30) ----------------
__global__ __launch_bounds__(128) void conv_kernel(
    const float* __restrict__ X, const float* __restrict__ conv_w,
    const float* __restrict__ conv_b, const float* __restrict__ convl_w,
    const float* __restrict__ convl_b, float* __restrict__ r_l) {
  int tid = threadIdx.x;
  int n0 = blockIdx.x * 8;
  int b = n0 >> 9, m0 = n0 & 511;
  __shared__ float xs[8][16][20];
  __shared__ float cw[3200];
  __shared__ float clw[1600];
  for (int idx = tid; idx < 3200; idx += 128) cw[idx] = conv_w[idx];
  for (int idx = tid; idx < 1600; idx += 128) clw[idx] = convl_w[idx];
  for (int w = 0; w < 20; ++w)
    xs[tid >> 4][tid & 15][w] = X[((long)(b * 20 + w) * 512 + m0) * 16 + tid];
  __syncthreads();
  if (tid < 80) {
    int s = tid / 10, k = tid % 10;
    float a0 = conv_b[k];
    float l0 = convl_b[k], l1 = convl_b[k];
    for (int f = 0; f < 16; ++f) {
#pragma unroll
      for (int w = 0; w < 20; ++w) a0 = fmaf(xs[s][f][w], cw[k * 320 + f * 20 + w], a0);
#pragma unroll
      for (int q = 0; q < 10; ++q) {
        float wv = clw[k * 160 + f * 10 + q];
        l0 = fmaf(xs[s][f][2 * q], wv, l0);
        l1 = fmaf(xs[s][f][2 * q + 1], wv, l1);
      }
    }
    long base = (long)(n0 + s) * 30 + k * 3;
    r_l[base + 0] = reluf_(a0);
    r_l[base + 1] = reluf_(l0);
    r_l[base + 2] = reluf_(l1);
  }
}

// ---------------- t1 = r_l @ gc1_W  (4 rows/block) ----------------
__global__ __launch_bounds__(128) void t1_kernel(const float* __restrict__ r_l,
                                                 const float* __restrict__ gc1_W,
                                                 float* __restrict__ t1) {
  int r0 = blockIdx.x * 4;
  int h = threadIdx.x;
  __shared__ float rs[4][30];
  if (h < 120) rs[h / 30][h % 30] = r_l[(long)r0 * 30 + h];
  __syncthreads();
  float a0 = 0, a1 = 0, a2 = 0, a3 = 0;
#pragma unroll
  for (int q = 0; q < 30; ++q) {
    float w = gc1_W[q * 128 + h];
    a0 = fmaf(rs[0][q], w, a0);
    a1 = fmaf(rs[1][q], w, a1);
    a2 = fmaf(rs[2][q], w, a2);
    a3 = fmaf(rs[3][q], w, a3);
  }
  t1[(long)(r0 + 0) * 128 + h] = a0;
  t1[(long)(r0 + 1) * 128 + h] = a1;
  t1[(long)(r0 + 2) * 128 + h] = a2;
  t1[(long)(r0 + 3) * 128 + h] = a3;
}

// ---------------- gemm: c = sigmoid(amx@Wb + wb); A = adj*c + amx*(1-c) ----------------
__global__ __launch_bounds__(256) void gemm_cA(
    const float* __restrict__ amx, const float* __restrict__ Wb,
    const float* __restrict__ adj, const float* __restrict__ wb,
    float* __restrict__ A) {
  const int bz = blockIdx.z;
  const int i0 = blockIdx.y * 64;
  const int j0 = blockIdx.x * 64;
  const int tid = threadIdx.x;
  const int ti = tid >> 4, tj = tid & 15;
  __shared__ float As[16][64];
  __shared__ float Bs[16][64];
  float acc[4][4] = {};
  const float* Abase = amx + (long)bz * 512 * 512;
  for (int kk0 = 0; kk0 < 512; kk0 += 16) {
    __syncthreads();
    {
      int il = tid >> 2, kq = (tid & 3) * 4;
      float4 v = *(const float4*)&Abase[(long)(i0 + il) * 512 + kk0 + kq];
      As[kq + 0][il] = v.x; As[kq + 1][il] = v.y;
      As[kq + 2][il] = v.z; As[kq + 3][il] = v.w;
      int kk = tid >> 4, jl = (tid & 15) * 4;
      *(float4*)&Bs[kk][jl] = *(const float4*)&Wb[(long)(kk0 + kk) * 512 + j0 + jl];
    }
    __syncthreads();
#pragma unroll
    for (int k = 0; k < 16; ++k) {
      float4 a4 = *(const float4*)&As[k][ti * 4];
      float4 b4 = *(const float4*)&Bs[k][tj * 4];
      float av[4] = {a4.x, a4.y, a4.z, a4.w};
      float bw[4] = {b4.x, b4.y, b4.z, b4.w};
#pragma unroll
      for (int a = 0; a < 4; ++a)
#pragma unroll
        for (int c = 0; c < 4; ++c) acc[a][c] = fmaf(av[a], bw[c], acc[a][c]);
    }
  }
  const float wbv = wb[0];
#pragma unroll
  for (int a = 0; a < 4; ++a) {
    int i = i0 + ti * 4 + a;
    long idx4 = (long)bz * 512 * 512 + (long)i * 512 + j0 + tj * 4;
    float4 am = *(const float4*)&amx[idx4];
    float4 ad = *(const float4*)&adj[(long)i * 512 + j0 + tj * 4];
    float4 o;
    float c0 = sigmoidf_(acc[a][0] + wbv);
    float c1 = sigmoidf_(acc[a][1] + wbv);
    float c2 = sigmoidf_(acc[a][2] + wbv);
    float c3 = sigmoidf_(acc[a][3] + wbv);
    o.x = ad.x * c0 + am.x * (1.f - c0);
    o.y = ad.y * c1 + am.y * (1.f - c1);
    o.z = ad.z * c2 + am.z * (1.f - c2);
    o.w = ad.w * c3 + am.w * (1.f - c3);
    *(float4*)&A[idx4] = o;
  }
}

// ---------------- gemm: h1 = relu(A @ t1 + gc1_b) ----------------
__global__ __launch_bounds__(256) void gemm_h1(
    const float* __restrict__ A, const float* __restrict__ t1,
    const float* __restrict__ gc1_b, float* __restrict__ h1) {
  const int bz = blockIdx.z;
  const int i0 = blockIdx.y * 64;
  const int j0 = blockIdx.x * 64;   // within 128
  const int tid = threadIdx.x;
  const int ti = tid >> 4, tj = tid & 15;
  __shared__ float As[16][64];
  __shared__ float Bs[16][64];
  float acc[4][4] = {};
  const float* Abase = A + (long)bz * 512 * 512;
  const float* Bbase = t1 + (long)bz * 512 * 128;
  for (int kk0 = 0; kk0 < 512; kk0 += 16) {
    __syncthreads();
    {
      int il = tid >> 2, kq = (tid & 3) * 4;
      float4 v = *(const float4*)&Abase[(long)(i0 + il) * 512 + kk0 + kq];
      As[kq + 0][il] = v.x; As[kq + 1][il] = v.y;
      As[kq + 2][il] = v.z; As[kq + 3][il] = v.w;
      int kk = tid >> 4, jl = (tid & 15) * 4;
      *(float4*)&Bs[kk][jl] = *(const float4*)&Bbase[(long)(kk0 + kk) * 128 + j0 + jl];
    }
    __syncthreads();
#pragma unroll
    for (int k = 0; k < 16; ++k) {
      float4 a4 = *(const float4*)&As[k][ti * 4];
      float4 b4 = *(const float4*)&Bs[k][tj * 4];
      float av[4] = {a4.x, a4.y, a4.z, a4.w};
      float bw[4] = {b4.x, b4.y, b4.z, b4.w};
#pragma unroll
      for (int a = 0; a < 4; ++a)
#pragma unroll
        for (int c = 0; c < 4; ++c) acc[a][c] = fmaf(av[a], bw[c], acc[a][c]);
    }
  }
#pragma unroll
  for (int a = 0; a < 4; ++a) {
    int i = i0 + ti * 4 + a;
    int jj = j0 + tj * 4;
    float4 o;
    o.x = reluf_(acc[a][0] + gc1_b[jj + 0]);
    o.y = reluf_(acc[a][1] + gc1_b[jj + 1]);
    o.z = reluf_(acc[a][2] + gc1_b[jj + 2]);
    o.w = reluf_(acc[a][3] + gc1_b[jj + 3]);
    *(float4*)&h1[((long)bz * 512 + i) * 128 + jj] = o;
  }
}

// ---------------- t2 = h1 @ gc2_W (16 rows/block) ----------------
__global__ __launch_bounds__(256) void t2_kernel(const float* __restrict__ h1,
                                                 const float* __restrict__ gc2_W,
                                                 float* __restrict__ t2) {
  int tid = threadIdx.x;
  int r0 = blockIdx.x * 16;
  __shared__ float hs[16 * 129];
  __shared__ float wsh[1280];
  for (int idx = tid; idx < 2048; idx += 256) {
    int r = idx >> 7, k = idx & 127;
    hs[r * 129 + k] = h1[(long)(r0 + r) * 128 + k];
  }
  for (int idx = tid; idx < 1280; idx += 256) wsh[idx] = gc2_W[idx];
  __syncthreads();
  if (tid < 160) {
    int r = tid / 10, c = tid % 10;
    float a = 0.f;
#pragma unroll 4
    for (int k = 0; k < 128; ++k) a = fmaf(hs[r * 129 + k], wsh[k * 10 + c], a);
    t2[(long)(r0 + r) * 10 + c] = a;
  }
}

// ---------------- out_spatial = relu(A @ t2 + gc2_b) ----------------
__global__ __launch_bounds__(256) void spat_kernel(
    const float* __restrict__ A, const float* __restrict__ t2,
    const float* __restrict__ gc2_b, float* __restrict__ osp) {
  int tid = threadIdx.x;
  int bz = blockIdx.y;
  int i0 = blockIdx.x * 64;
  __shared__ float t2s[5120];
  __shared__ float As[64 * 33];
  for (int idx = tid; idx < 5120; idx += 256) t2s[idx] = t2[(long)bz * 5120 + idx];
  int il = tid >> 2, cg = tid & 3;
  float a0 = 0, a1 = 0, a2 = 0;
  const float* Ab = A + (long)bz * 512 * 512;
  for (int kk0 = 0; kk0 < 512; kk0 += 32) {
    __syncthreads();
    for (int idx = tid; idx < 2048; idx += 256) {
      int r = idx >> 5, k = idx & 31;
      As[r * 33 + k] = Ab[(long)(i0 + r) * 512 + kk0 + k];
    }
    __syncthreads();
#pragma unroll 4
    for (int kk = 0; kk < 32; ++kk) {
      float av = As[il * 33 + kk];
      const float* tp = &t2s[(kk0 + kk) * 10];
      a0 = fmaf(av, tp[cg], a0);
      a1 = fmaf(av, tp[cg + 4], a1);
      if (cg < 2) a2 = fmaf(av, tp[cg + 8], a2);
    }
  }
  long ob = (long)(bz * 512 + i0 + il) * 10;
  osp[ob + cg] = reluf_(a0 + gc2_b[cg]);
  osp[ob + cg + 4] = reluf_(a1 + gc2_b[cg + 4]);
  if (cg < 2) osp[ob + cg + 8] = reluf_(a2 + gc2_b[cg + 8]);
}

// ---------------- readout + BCE loss ----------------
__global__ __launch_bounds__(256) void readout_kernel(
    const float* __restrict__ osp, const float* __restrict__ last_hid,
    const float* __restrict__ out_W, const float* __restrict__ out_b,
    const float* __restrict__ Y, float* __restrict__ d_out) {
  int tid = threadIdx.x;
  int gid = blockIdx.x * 256 + tid;  // 0..4095
  __shared__ float wS[138];
  for (int idx = tid; idx < 138; idx += 256) wS[idx] = out_W[idx];
  __syncthreads();
  float y = out_b[0];
  const float* sp = &osp[(long)gid * 10];
#pragma unroll
  for (int k = 0; k < 10; ++k) y = fmaf(sp[k], wS[k], y);
  const float* hp = &last_hid[(long)gid * 128];
  for (int h = 0; h < 128; h += 4) {
    float4 hv = *(const float4*)&hp[h];
    y = fmaf(hv.x, wS[10 + h + 0], y);
    y = fmaf(hv.y, wS[10 + h + 1], y);
    y = fmaf(hv.z, wS[10 + h + 2], y);
    y = fmaf(hv.w, wS[10 + h + 3], y);
  }
  d_out[1 + gid] = sigmoidf_(y);
  float l = fmaxf(y, 0.f) + log1pf(__expf(-fabsf(y))) - Y[gid] * y;
  for (int off = 32; off > 0; off >>= 1) l += __shfl_down(l, off);
  __shared__ float red[4];
  if ((tid & 63) == 0) red[tid >> 6] = l;
  __syncthreads();
  if (tid == 0)
    atomicAdd(d_out, (red[0] + red[1] + red[2] + red[3]) * (1.0f / 4096.f));
}

// ---------------- launcher ----------------
extern "C" void kernel_launch(void* const* d_in, const int* in_sizes, int n_in,
                              void* d_out, int out_size, void* d_ws, size_t ws_size,
                              hipStream_t stream) {
  const float* X       = (const float*)d_in[0];
  const float* Y       = (const float*)d_in[1];
  const float* adj     = (const float*)d_in[2];
  const float* V       = (const float*)d_in[3];
  const float* bv      = (const float*)d_in[4];
  const float* W1      = (const float*)d_in[5];
  const float* b1      = (const float*)d_in[6];
  const float* W2      = (const float*)d_in[7];
  const float* Wb      = (const float*)d_in[8];
  const float* wb      = (const float*)d_in[9];
  const float* conv_w  = (const float*)d_in[10];
  const float* conv_b  = (const float*)d_in[11];
  const float* convl_w = (const float*)d_in[12];
  const float* convl_b = (const float*)d_in[13];
  const float* gWih    = (const float*)d_in[14];
  const float* gWhh    = (const float*)d_in[15];
  const float* gbih    = (const float*)d_in[16];
  const float* gbhh    = (const float*)d_in[17];
  const float* gc1_W   = (const float*)d_in[18];
  const float* gc1_b   = (const float*)d_in[19];
  const float* gc2_W   = (const float*)d_in[20];
  const float* gc2_b   = (const float*)d_in[21];
  const float* out_W   = (const float*)d_in[22];
  const float* out_b   = (const float*)d_in[23];
  float* out = (float*)d_out;

  float* ws = (float*)d_ws;
  float* WhhT  = ws; ws += 49152;
  float* lhid  = ws; ws += 524288;
  float* p1    = ws; ws += 262144;
  float* p2    = ws; ws += 262144;
  float* amx   = ws; ws += 2097152;
  float* scl   = ws; ws += 4096;
  float* r_l   = ws; ws += 122880;
  float* Abuf  = ws; ws += 2097152;
  float* t1    = ws; ws += 524288;
  float* h1    = ws; ws += 524288;
  float* t2    = ws; ws += 40960;
  float* osp   = ws; ws += 40960;
  if (ws_size < (size_t)(ws - (float*)d_ws) * sizeof(float)) return;

  whht_kernel<<<192, 256, 0, stream>>>(gWhh, WhhT);
  gru_kernel<<<512, 384, 0, stream>>>(X, WhhT, gWih, gbih, gbhh, lhid);
  attn_p_kernel<<<1024, 128, 0, stream>>>(lhid, W1, W2, b1, p1, p2);
  amx_kernel<<<dim3(32, 32, 8), 256, 0, stream>>>(p1, p2, V, bv, amx);
  colnorm_kernel<<<dim3(16, 8), 256, 0, stream>>>(amx, scl);
  scale_kernel<<<2048, 256, 0, stream>>>(amx, scl);
  conv_kernel<<<512, 128, 0, stream>>>(X, conv_w, conv_b, convl_w, convl_b, r_l);
  t1_kernel<<<1024, 128, 0, stream>>>(r_l, gc1_W, t1);
  gemm_cA<<<dim3(8, 8, 8), 256, 0, stream>>>(amx, Wb, adj, wb, Abuf);
  gemm_h1<<<dim3(2, 8, 8), 256, 0, stream>>>(Abuf, t1, gc1_b, h1);
  t2_kernel<<<256, 256, 0, stream>>>(h1, gc2_W, t2);
  spat_kernel<<<dim3(8, 8), 256, 0, stream>>>(Abuf, t2, gc2_b, osp);
  hipMemsetAsync(d_out, 0, sizeof(float), stream);
  readout_kernel<<<16, 256, 0, stream>>>(osp, lhid, out_W, out_b, Y, out);
}